// Round 1
// 744.614 us; speedup vs baseline: 1.0066x; 1.0066x over previous
//
#include <hip/hip_runtime.h>
#include <math.h>

#define H 512
#define W 640
#define LPATCH 1280   // (512/16)*(640/16)
#define WBLK 40       // 640/16
#define NIMG 4
#define CDESC 128
#define PLANE ((size_t)H * W)

// output offsets (floats)
#define OFF_K2D 0
#define OFF_COORDS 10240                    // 4*1280*2
#define OFF_DESC  (10240 + 15360)           // + 4*3*1280
#define OFF_WGT   (10240 + 15360 + 655360)  // + 4*128*1280

// Bilinear tap record: 4 weights (validity folded in) + 4 clipped offsets.
// Matches F.grid_sample(align_corners=False, padding_mode='zeros').
__device__ __forceinline__ void make_taps(
    float eu, float ev,
    float& w00, float& w10, float& w01, float& w11,
    int& o00, int& o10, int& o01, int& o11)
{
    // exact reference arithmetic (do NOT algebraically simplify: keeps
    // bit-compat with the JAX ref path through u_norm/v_norm)
    const float un = 2.0f * eu / (float)(W - 1) - 1.0f;
    const float vn = 2.0f * ev / (float)(H - 1) - 1.0f;
    const float x = ((un + 1.0f) * (float)W - 1.0f) * 0.5f;
    const float y = ((vn + 1.0f) * (float)H - 1.0f) * 0.5f;
    const float x0 = floorf(x), y0 = floorf(y);
    const float x1 = x0 + 1.0f, y1 = y0 + 1.0f;
    const float wx1 = x - x0, wx0 = 1.0f - wx1;
    const float wy1 = y - y0, wy0 = 1.0f - wy1;

    const bool vx0 = (x0 >= 0.0f) && (x0 <= (float)(W - 1));
    const bool vx1 = (x1 >= 0.0f) && (x1 <= (float)(W - 1));
    const bool vy0 = (y0 >= 0.0f) && (y0 <= (float)(H - 1));
    const bool vy1 = (y1 >= 0.0f) && (y1 <= (float)(H - 1));

    w00 = (vx0 && vy0) ? wx0 * wy0 : 0.0f;
    w10 = (vx1 && vy0) ? wx1 * wy0 : 0.0f;
    w01 = (vx0 && vy1) ? wx0 * wy1 : 0.0f;
    w11 = (vx1 && vy1) ? wx1 * wy1 : 0.0f;

    int xi0 = (int)x0; xi0 = xi0 < 0 ? 0 : (xi0 > W - 1 ? W - 1 : xi0);
    int xi1 = (int)x1; xi1 = xi1 < 0 ? 0 : (xi1 > W - 1 ? W - 1 : xi1);
    int yi0 = (int)y0; yi0 = yi0 < 0 ? 0 : (yi0 > H - 1 ? H - 1 : yi0);
    int yi1 = (int)y1; yi1 = yi1 < 0 ? 0 : (yi1 > H - 1 ? H - 1 : yi1);

    o00 = yi0 * W + xi0;
    o10 = yi0 * W + xi1;
    o01 = yi1 * W + xi0;
    o11 = yi1 * W + xi1;
}

// Kernel A: one WAVE per patch (was one block per patch).
// Each lane owns 4 consecutive pixels of a patch row -> aligned float4 loads
// (wb*16 is 64B-aligned, pj0 in {0,4,8,12}). No LDS, no __syncthreads:
// the whole softmax + 6 weighted sums reduce in a single 64-lane butterfly.
// Lane 0 also emits the bilinear tap record to d_ws so kernel B doesn't
// recompute the setup 33x per point.
__global__ __launch_bounds__(256) void kp_attn(
    const float* __restrict__ geom,   // [N,3,H,W]
    const float* __restrict__ det,    // [N,1,H,W]
    float* __restrict__ out,
    float4* __restrict__ ws)          // 2 x float4 per point (may be null)
{
    const int t = threadIdx.x;
    const int wid = t >> 6;
    const int lane = t & 63;
    const int wave = blockIdx.x * 4 + wid;   // n*LPATCH + l, in [0,5120)
    const int n = wave / LPATCH;
    const int l = wave - n * LPATCH;
    const int hb = l / WBLK;
    const int wb = l - hb * WBLK;
    const int pi = lane >> 2;          // patch row 0..15
    const int pj0 = (lane & 3) << 2;   // patch col 0,4,8,12
    const int v = hb * 16 + pi;
    const int u0 = wb * 16 + pj0;
    const size_t pix = (size_t)v * W + u0;

    const float* gb = geom + (size_t)n * 3 * PLANE + pix;
    const float4 g0 = *(const float4*)(gb);
    const float4 g1 = *(const float4*)(gb + PLANE);
    const float4 g2 = *(const float4*)(gb + 2 * PLANE);
    const float4 dv = *(const float4*)(det + (size_t)n * PLANE + pix);

    float s[4]  = { dv.x, dv.y, dv.z, dv.w };
    const float ga[4] = { g0.x, g0.y, g0.z, g0.w };
    const float gbv[4] = { g1.x, g1.y, g1.z, g1.w };
    const float gc[4] = { g2.x, g2.y, g2.z, g2.w };
    #pragma unroll
    for (int j = 0; j < 4; ++j)
        if (ga[j] * ga[j] + gbv[j] * gbv[j] + gc[j] * gc[j] == 0.0f) s[j] = -20.0f;

    // patch max
    float m = fmaxf(fmaxf(s[0], s[1]), fmaxf(s[2], s[3]));
    #pragma unroll
    for (int off = 32; off > 0; off >>= 1) m = fmaxf(m, __shfl_xor(m, off, 64));

    // 6 weighted sums: 1, u, v, g0, g1, g2
    float a0 = 0.f, a1 = 0.f, a3 = 0.f, a4 = 0.f, a5 = 0.f;
    #pragma unroll
    for (int j = 0; j < 4; ++j) {
        const float e = __expf(s[j] - m);
        a0 += e;
        a1 += e * (float)(u0 + j);
        a3 += e * ga[j];
        a4 += e * gbv[j];
        a5 += e * gc[j];
    }
    float a2 = (float)v * a0;   // v is constant per lane

    #pragma unroll
    for (int off = 32; off > 0; off >>= 1) {
        a0 += __shfl_xor(a0, off, 64);
        a1 += __shfl_xor(a1, off, 64);
        a2 += __shfl_xor(a2, off, 64);
        a3 += __shfl_xor(a3, off, 64);
        a4 += __shfl_xor(a4, off, 64);
        a5 += __shfl_xor(a5, off, 64);
    }

    // butterfly leaves totals in every lane; taps computed wave-uniform,
    // stores done by lane 0 only.
    const float inv = 1.0f / a0;
    const float eu = a1 * inv;
    const float ev = a2 * inv;

    float w00, w10, w01, w11;
    int o00, o10, o01, o11;
    make_taps(eu, ev, w00, w10, w01, w11, o00, o10, o01, o11);

    if (lane == 0) {
        float* k2 = out + OFF_K2D + (size_t)wave * 2;
        k2[0] = eu;
        k2[1] = ev;
        float* oc = out + OFF_COORDS + (size_t)n * 3 * LPATCH + l;
        oc[0]          = a3 * inv;
        oc[LPATCH]     = a4 * inv;
        oc[2 * LPATCH] = a5 * inv;
        if (ws) {
            ws[2 * wave] = make_float4(w00, w10, w01, w11);
            ((int4*)ws)[2 * wave + 1] = make_int4(o00, o10, o01, o11);
        }
    }
}

// Kernel B: bilinear gather, 4 channels per thread (cg, cg+32, cg+64, cg+96)
// -> 16 independent loads in flight. Tap record read from ws (2 coalesced
// 16B loads) instead of recomputing the normalize/floor/clip chain per block.
__global__ __launch_bounds__(256) void kp_sample(
    const float* __restrict__ desc,   // [N,128,H,W]
    const float* __restrict__ wsc,    // [N,1,H,W]
    const float4* __restrict__ ws,
    float* __restrict__ out)
{
    int blk = blockIdx.x;
    const int lb = blk % 5;  blk /= 5;
    const int cg = blk % 33;
    const int n  = blk / 33;
    const int l  = lb * 256 + threadIdx.x;
    const int idx = n * LPATCH + l;

    const float4 wv = ws[2 * idx];
    const int4  ov = ((const int4*)ws)[2 * idx + 1];

    if (cg < 32) {
        const float* p = desc + ((size_t)n * CDESC + cg) * PLANE;
        float r[4];
        #pragma unroll
        for (int k = 0; k < 4; ++k) {
            const float* pk = p + (size_t)k * 32 * PLANE;
            const float t00 = pk[ov.x];
            const float t10 = pk[ov.y];
            const float t01 = pk[ov.z];
            const float t11 = pk[ov.w];
            r[k] = t00 * wv.x + t10 * wv.y + t01 * wv.z + t11 * wv.w;
        }
        float* op = out + OFF_DESC + ((size_t)n * CDESC + cg) * LPATCH + l;
        #pragma unroll
        for (int k = 0; k < 4; ++k) op[(size_t)k * 32 * LPATCH] = r[k];
    } else {
        const float* p = wsc + (size_t)n * PLANE;
        out[OFF_WGT + (size_t)n * LPATCH + l] =
            p[ov.x] * wv.x + p[ov.y] * wv.y + p[ov.z] * wv.z + p[ov.w] * wv.w;
    }
}

// Fallback (ws too small): recompute taps from k2 in out. Not expected to run.
__global__ __launch_bounds__(256) void kp_sample_k2(
    const float* __restrict__ desc,
    const float* __restrict__ wsc,
    float* __restrict__ out)
{
    int blk = blockIdx.x;
    const int lb = blk % 5;  blk /= 5;
    const int cg = blk % 33;
    const int n  = blk / 33;
    const int l  = lb * 256 + threadIdx.x;

    const float* k2 = out + OFF_K2D + ((size_t)n * LPATCH + l) * 2;
    float w00, w10, w01, w11;
    int o00, o10, o01, o11;
    make_taps(k2[0], k2[1], w00, w10, w01, w11, o00, o10, o01, o11);

    if (cg < 32) {
        const float* p = desc + ((size_t)n * CDESC + cg) * PLANE;
        float r[4];
        #pragma unroll
        for (int k = 0; k < 4; ++k) {
            const float* pk = p + (size_t)k * 32 * PLANE;
            r[k] = pk[o00] * w00 + pk[o10] * w10 + pk[o01] * w01 + pk[o11] * w11;
        }
        float* op = out + OFF_DESC + ((size_t)n * CDESC + cg) * LPATCH + l;
        #pragma unroll
        for (int k = 0; k < 4; ++k) op[(size_t)k * 32 * LPATCH] = r[k];
    } else {
        const float* p = wsc + (size_t)n * PLANE;
        out[OFF_WGT + (size_t)n * LPATCH + l] =
            p[o00] * w00 + p[o10] * w10 + p[o01] * w01 + p[o11] * w11;
    }
}

extern "C" void kernel_launch(void* const* d_in, const int* in_sizes, int n_in,
                              void* d_out, int out_size, void* d_ws, size_t ws_size,
                              hipStream_t stream) {
    const float* geom = (const float*)d_in[0];   // geometry_img  [4,3,512,640]
    const float* desc = (const float*)d_in[1];   // descriptors   [4,128,512,640]
    const float* det  = (const float*)d_in[2];   // detector_scores [4,1,512,640]
    const float* wsc  = (const float*)d_in[3];   // weight_scores [4,1,512,640]
    float* out = (float*)d_out;

    const size_t ws_needed = (size_t)NIMG * LPATCH * 32;  // 160 KB of tap records
    const bool use_ws = (d_ws != nullptr) && (ws_size >= ws_needed);

    // 5120 waves = 1280 blocks x 4 waves; one wave per patch
    kp_attn<<<1280, 256, 0, stream>>>(geom, det, out,
                                      use_ws ? (float4*)d_ws : nullptr);
    if (use_ws)
        kp_sample<<<NIMG * 33 * 5, 256, 0, stream>>>(desc, wsc,
                                                     (const float4*)d_ws, out);
    else
        kp_sample_k2<<<NIMG * 33 * 5, 256, 0, stream>>>(desc, wsc, out);
}